// Round 6
// baseline (17.479 us; speedup 1.0000x reference)
//
#include <hip/hip_runtime.h>
#include <hip/hip_bf16.h>

// AngleTensor: out[b,i,j,k] = mask * arccos( (p_j - p_i) . (p_k - p_i) / (d_ij * d_ik) )
// mask = 0 when i==j || i==k || j==k; mag < 1e-10 -> mag = 1.
// positions: (B,N,3) f32, dist: (B,N,N) f32, out: (B,N,N,N) f32.
//
// cos = u_j . u_k with u_t = (p_t - p_i) * rcp(max(d_it, 1e-7)), staged in LDS.
// j==k (i!=j): c = |u_j|^2 -> clamp 1 -> acos = 0 (mask arithmetic).
// i==j / i==k: forced c=1 via hoisted select.
// Math packed as 2x f32 pairs to hit v_pk_fma_f32 / v_pk_mul_f32 (gfx950 packed fp32).

#define PI_F 3.14159265358979323846f

typedef float f32x2 __attribute__((ext_vector_type(2)));
typedef float f32x4 __attribute__((ext_vector_type(4)));

__device__ __forceinline__ f32x2 pk_fma(f32x2 a, f32x2 b, f32x2 c) {
    return __builtin_elementwise_fma(a, b, c);
}

// Quadratic minimax for acos(x)/sqrt(1-x) on [0,1]; endpoints exact:
// p(0)=pi/2, p(1)=sqrt(2). |angle err| <= ~1e-3 rad. c==1 -> exact 0.
#define A0C 1.5707963f
#define A1C (-0.2025900f)
#define A2C 0.0460080f

// acos on a pair, inputs pre-clamped to [-1,1].
__device__ __forceinline__ f32x2 acos2(f32x2 c) {
    f32x2 ax;
    ax.x = fabsf(c.x);
    ax.y = fabsf(c.y);
    const f32x2 a2 = {A2C, A2C}, a1 = {A1C, A1C}, a0 = {A0C, A0C};
    f32x2 p = pk_fma(ax, pk_fma(ax, a2, a1), a0);
    const f32x2 negone = {-1.0f, -1.0f}, one = {1.0f, 1.0f}, pi2 = {PI_F, PI_F};
    f32x2 om = pk_fma(ax, negone, one);          // 1 - ax  (>= 0)
    f32x2 s;
    s.x = __builtin_amdgcn_sqrtf(om.x);
    s.y = __builtin_amdgcn_sqrtf(om.y);
    f32x2 r = s * p;                             // v_pk_mul_f32
    f32x2 pir = pk_fma(r, negone, pi2);          // pi - r
    f32x2 out;
    out.x = (c.x < 0.0f) ? pir.x : r.x;
    out.y = (c.y < 0.0f) ? pir.y : r.y;
    return out;
}

__device__ __forceinline__ float prep(float craw, bool valid) {
    float c = __builtin_amdgcn_fmed3f(craw, -1.0f, 1.0f);
    return valid ? c : 1.0f;                     // masked -> acos gives exact 0
}

// Register-resident kernel for N % 4 == 0, N <= 128.
// Block = 256 threads handles one (b,i); quarter jj owns rows j = jj + 8*s + 16*t;
// lane kq = tid&31 owns k = 4*kq..4*kq+3, unit vectors held in registers throughout.
__global__ __launch_bounds__(256) void angle_unit(const float* __restrict__ pos,
                                                  const float* __restrict__ dist,
                                                  float* __restrict__ out, int N) {
    extern __shared__ float smem[];
    float* sux = smem;
    float* suy = smem + N;
    float* suz = smem + 2 * N;

    const int i = blockIdx.x;
    const int b = blockIdx.y;
    const int s = blockIdx.z;

    const float* pb   = pos  + (size_t)b * N * 3;
    const float* drow = dist + ((size_t)b * N + i) * N;

    const float pix = pb[3 * i + 0];
    const float piy = pb[3 * i + 1];
    const float piz = pb[3 * i + 2];

    for (int t = threadIdx.x; t < N; t += blockDim.x) {
        const float dx = pb[3 * t + 0] - pix;
        const float dy = pb[3 * t + 1] - piy;
        const float dz = pb[3 * t + 2] - piz;
        const float r  = __builtin_amdgcn_rcpf(fmaxf(drow[t], 1e-7f));
        sux[t] = dx * r;   // t == i: dx = 0 exactly -> u = 0 (handled by mask select)
        suy[t] = dy * r;
        suz[t] = dz * r;
    }
    __syncthreads();

    const int kq = threadIdx.x & 31;
    const int jj = threadIdx.x >> 5;
    const int k0 = kq * 4;
    const bool klive = (k0 + 3 < N);

    // k unit vectors pinned in registers as pairs (01, 23).
    f32x2 kx01 = {0, 0}, ky01 = kx01, kz01 = kx01;
    f32x2 kx23 = kx01, ky23 = kx01, kz23 = kx01;
    if (klive) {
        const f32x4 vx = *reinterpret_cast<const f32x4*>(&sux[k0]);
        const f32x4 vy = *reinterpret_cast<const f32x4*>(&suy[k0]);
        const f32x4 vz = *reinterpret_cast<const f32x4*>(&suz[k0]);
        kx01.x = vx.x; kx01.y = vx.y; kx23.x = vx.z; kx23.y = vx.w;
        ky01.x = vy.x; ky01.y = vy.y; ky23.x = vy.z; ky23.y = vy.w;
        kz01.x = vz.x; kz01.y = vz.y; kz23.x = vz.z; kz23.y = vz.w;
    }
    // (k != i): j-invariant, hoisted.
    const bool ki0 = (k0 + 0) != i;
    const bool ki1 = (k0 + 1) != i;
    const bool ki2 = (k0 + 2) != i;
    const bool ki3 = (k0 + 3) != i;

    float* obase = out + ((size_t)b * N + i) * (size_t)N * (size_t)N;

    auto do_row = [&](int j) {
        const float ujx = sux[j];   // same-address LDS broadcast within the quarter
        const float ujy = suy[j];
        const float ujz = suz[j];
        const bool  jne = (j != i);
        const f32x2 jx = {ujx, ujx}, jy = {ujy, ujy}, jz = {ujz, ujz};

        f32x2 c01 = pk_fma(jx, kx01, pk_fma(jy, ky01, jz * kz01));
        f32x2 c23 = pk_fma(jx, kx23, pk_fma(jy, ky23, jz * kz23));

        c01.x = prep(c01.x, jne && ki0);
        c01.y = prep(c01.y, jne && ki1);
        c23.x = prep(c23.x, jne && ki2);
        c23.y = prep(c23.y, jne && ki3);

        const f32x2 a01 = acos2(c01);
        const f32x2 a23 = acos2(c23);

        if (klive) {
            f32x4 r;
            r.x = a01.x; r.y = a01.y; r.z = a23.x; r.w = a23.y;
            *reinterpret_cast<f32x4*>(obase + (size_t)j * N + k0) = r;  // plain store (nt reverted)
        }
    };

    // rows j = jj + 8*s + 16*t, unrolled x2 for broadcast-latency overlap.
    for (int j = jj + 8 * s; j < N; j += 32) {
        do_row(j);
        if (j + 16 < N) do_row(j + 16);
    }
}

// Generic scalar fallback (any N), grid-stride over all B*N^3 elements.
__global__ void angle_scalar(const float* __restrict__ pos,
                             const float* __restrict__ dist,
                             float* __restrict__ out, int N, long long total) {
    const long long NN  = (long long)N * N;
    const long long NNN = NN * N;
    for (long long idx = (long long)blockIdx.x * blockDim.x + threadIdx.x;
         idx < total; idx += (long long)gridDim.x * blockDim.x) {
        int k = (int)(idx % N);
        int j = (int)((idx / N) % N);
        int i = (int)((idx / NN) % N);
        int b = (int)(idx / NNN);

        const float* pb   = pos  + (size_t)b * N * 3;
        const float* drow = dist + ((size_t)b * N + i) * N;

        float pix = pb[i * 3 + 0], piy = pb[i * 3 + 1], piz = pb[i * 3 + 2];
        float rj = __builtin_amdgcn_rcpf(fmaxf(drow[j], 1e-7f));
        float rk = __builtin_amdgcn_rcpf(fmaxf(drow[k], 1e-7f));
        float ujx = (pb[j * 3 + 0] - pix) * rj, ujy = (pb[j * 3 + 1] - piy) * rj,
              ujz = (pb[j * 3 + 2] - piz) * rj;
        float ukx = (pb[k * 3 + 0] - pix) * rk, uky = (pb[k * 3 + 1] - piy) * rk,
              ukz = (pb[k * 3 + 2] - piz) * rk;
        bool valid = (i != j) && (i != k);
        float craw = fmaf(ujx, ukx, fmaf(ujy, uky, ujz * ukz));
        float c = prep(craw, valid);
        f32x2 cp = {c, c};
        out[idx] = acos2(cp).x;
    }
}

extern "C" void kernel_launch(void* const* d_in, const int* in_sizes, int n_in,
                              void* d_out, int out_size, void* d_ws, size_t ws_size,
                              hipStream_t stream) {
    const float* pos  = (const float*)d_in[0];
    const float* dist = (const float*)d_in[1];
    float* out = (float*)d_out;

    const long long pos_sz  = in_sizes[0];  // B*N*3
    const long long dist_sz = in_sizes[1];  // B*N*N
    const int N = (int)((3LL * dist_sz) / pos_sz);
    const int B = (int)(pos_sz / (3LL * (long long)N));

    if (N > 0 && (N % 4) == 0 && N <= 128) {
        const int SPLIT = 2;                       // grid = 2048 blocks for B=8,N=128
        dim3 grid(N, B, SPLIT);
        size_t smem = (size_t)3 * N * sizeof(float);
        angle_unit<<<grid, dim3(256), smem, stream>>>(pos, dist, out, N);
    } else {
        const long long total = (long long)B * N * N * N;
        int blocks = (int)((total + 255) / 256);
        if (blocks > 131072) blocks = 131072;
        if (blocks < 1) blocks = 1;
        angle_scalar<<<blocks, dim3(256), 0, stream>>>(pos, dist, out, N, total);
    }
}